// Round 7
// baseline (246.474 us; speedup 1.0000x reference)
//
#include <hip/hip_runtime.h>
#include <hip/hip_bf16.h>

// IsolaCLIPLoss: out = 3*align + 0.5*(log-mean-exp uniformity of img Gram + txt Gram)
// N=8192, D=512 fp32 inputs.
//
// R7 changes vs R5 (R6 no-LDS experiment reverted — L1-thrash latency-bound):
//  - gram: A-panel persistent in REGISTERS (full K=512: av[2][8] = 128 VGPRs).
//    Block processes 4 consecutive triangular tiles (2080/4 = 520 blocks per
//    matrix, perfectly balanced; A restaged only on row-panel crossings).
//    Per tile: stage full-K 64KB B into LDS (16x global_load_lds rounds),
//    ONE barrier, 8 K-steps reading only B-fragments, ONE barrier.
//    LDS reads halve (B only), staging amortizes 4x, barriers 8/tile -> 2/tile.
//  - LDS row stride 512B; swizzle on low 3 bits of 16B-chunk idx (R5 family).
//  - __launch_bounds__(256,2): 2 blocks/CU (64KB LDS), VGPR capped at 256.

#define NROWS 8192
#define DBYTES 512         // row stride in bytes (fp8) == D
#define NT    64           // 8192/128 tiles per dim
#define NTILES 2080        // NT*(NT+1)/2 upper-triangular tiles
#define JTILES 4
#define NBLK (NTILES / JTILES)   // 520
#define SCALE_SPLAT 0x75757575   // E8M0 byte 117 = 2^-10, splatted

typedef __attribute__((ext_vector_type(8)))  int   int8v;
typedef __attribute__((ext_vector_type(4)))  int   int4v;
typedef __attribute__((ext_vector_type(16))) float float16v;

__device__ inline void load_lds16(const void* g, void* l) {
    __builtin_amdgcn_global_load_lds(
        (const __attribute__((address_space(1))) void*)g,
        (__attribute__((address_space(3))) void*)l, 16, 0, 0);
}

__device__ inline int swz(int r) { return (r ^ (r >> 3)) & 7; }
// physical 16B-chunk for logical chunk c (0..31) in row r
__device__ inline int chsw(int c, int r) { return (c & ~7) | ((c & 7) ^ swz(r)); }

// ---------------------------------------------------------------- normalize
__global__ __launch_bounds__(256) void normalize_kernel(
    const float* __restrict__ img, const float* __restrict__ txt,
    unsigned char* __restrict__ nimg, unsigned char* __restrict__ ntxt,
    float* __restrict__ alignp,   // [2048] per-block partial of sum_i ndot_i
    float* __restrict__ S)        // [64] gram accumulators -> zeroed here
{
    if (blockIdx.x == 0 && threadIdx.x < 64) S[threadIdx.x] = 0.0f;

    const int lane = threadIdx.x & 63;
    const int wave = threadIdx.x >> 6;
    const int row  = blockIdx.x * 4 + wave;

    const float4* pi = (const float4*)(img + (size_t)row * 512);
    const float4* pt = (const float4*)(txt + (size_t)row * 512);
    const float4 i0 = pi[lane], i1 = pi[lane + 64];
    const float4 t0 = pt[lane], t1 = pt[lane + 64];

    float ssi = i0.x*i0.x + i0.y*i0.y + i0.z*i0.z + i0.w*i0.w
              + i1.x*i1.x + i1.y*i1.y + i1.z*i1.z + i1.w*i1.w;
    float sst = t0.x*t0.x + t0.y*t0.y + t0.z*t0.z + t0.w*t0.w
              + t1.x*t1.x + t1.y*t1.y + t1.z*t1.z + t1.w*t1.w;
    float dot = i0.x*t0.x + i0.y*t0.y + i0.z*t0.z + i0.w*t0.w
              + i1.x*t1.x + i1.y*t1.y + i1.z*t1.z + i1.w*t1.w;

    #pragma unroll
    for (int off = 1; off < 64; off <<= 1) {
        ssi += __shfl_xor(ssi, off);
        sst += __shfl_xor(sst, off);
        dot += __shfl_xor(dot, off);
    }
    const float inv_i = 1.0f / fmaxf(sqrtf(ssi), 1e-12f);
    const float inv_t = 1.0f / fmaxf(sqrtf(sst), 1e-12f);
    const float si = 1024.0f * inv_i;   // quantize at 2^10 scale
    const float st = 1024.0f * inv_t;

    int p0 = __builtin_amdgcn_cvt_pk_fp8_f32(i0.x*si, i0.y*si, 0, false);
    p0     = __builtin_amdgcn_cvt_pk_fp8_f32(i0.z*si, i0.w*si, p0, true);
    int p1 = __builtin_amdgcn_cvt_pk_fp8_f32(i1.x*si, i1.y*si, 0, false);
    p1     = __builtin_amdgcn_cvt_pk_fp8_f32(i1.z*si, i1.w*si, p1, true);
    int q0 = __builtin_amdgcn_cvt_pk_fp8_f32(t0.x*st, t0.y*st, 0, false);
    q0     = __builtin_amdgcn_cvt_pk_fp8_f32(t0.z*st, t0.w*st, q0, true);
    int q1 = __builtin_amdgcn_cvt_pk_fp8_f32(t1.x*st, t1.y*st, 0, false);
    q1     = __builtin_amdgcn_cvt_pk_fp8_f32(t1.z*st, t1.w*st, q1, true);

    int* oi = (int*)(nimg + (size_t)row * DBYTES);
    int* ot = (int*)(ntxt + (size_t)row * DBYTES);
    oi[lane] = p0; oi[lane + 64] = p1;
    ot[lane] = q0; ot[lane + 64] = q1;

    __shared__ float r4[4];
    if (lane == 0) r4[wave] = dot * inv_i * inv_t;
    __syncthreads();
    if (threadIdx.x == 0)
        alignp[blockIdx.x] = r4[0] + r4[1] + r4[2] + r4[3];
}

// ---------------------------------------------------------------- gram + lme
__global__ __launch_bounds__(256, 2) void gram_kernel(
    const unsigned char* __restrict__ A0,   // fp8 [8192][512], blockIdx.y==0
    const unsigned char* __restrict__ A1,   // blockIdx.y==1
    float* __restrict__ S)                  // [64] spread accumulators
{
    const unsigned char* __restrict__ A = blockIdx.y ? A1 : A0;
    const int tid  = threadIdx.x;
    const int lane = tid & 63;
    const int wave = tid >> 6;
    const int wm = wave & 1, wn = wave >> 1;   // 2x2 wave grid over 128x128
    const int lr = lane & 31;                  // row-in-subtile
    const int h  = lane >> 5;                  // K-half select

    // First tile of this block's run of JTILES consecutive triangular tiles.
    const int t0i = blockIdx.x * JTILES;
    int i = (int)((129.0f - sqrtf(129.0f * 129.0f - 8.0f * (float)t0i)) * 0.5f);
    while ((i + 1) * (129 - (i + 1)) / 2 <= t0i) ++i;
    while (i * (129 - i) / 2 > t0i) --i;
    int j = i + (t0i - i * (129 - i) / 2);

    __shared__ __align__(16) unsigned char lds[128 * 512];   // 64 KB
    __shared__ float ps[4];

    // staging lane constants
    const int sr_off = tid >> 5;       // row-within-round-octet
    const int scp    = tid & 31;       // physical 16B chunk

    int8v av[2][8];                    // A-fragments, full K (128 VGPRs)
    int cur_i = -1;
    float s = 0.0f;                    // running weighted exp-sum (per lane)

    for (int tt = 0; tt < JTILES; ++tt) {
        __syncthreads();   // prior LDS readers done before we overwrite

        if (i != cur_i) {
            // ---- stage A panel i (64 KB), pull fragments into registers
            const unsigned char* gA = A + (size_t)i * 128 * DBYTES;
            #pragma unroll
            for (int rnd = 0; rnd < 16; ++rnd) {
                const int r  = rnd * 8 + sr_off;
                const int cl = chsw(scp, r);
                load_lds16(gA + (size_t)r * DBYTES + cl * 16,
                           &lds[r * DBYTES + scp * 16]);
            }
            __syncthreads();
            #pragma unroll
            for (int mt = 0; mt < 2; ++mt) {
                const int r = wm * 64 + mt * 32 + lr;
                #pragma unroll
                for (int ks = 0; ks < 8; ++ks) {
                    const int c = ks * 4 + h * 2;
                    const int4v q0 = *(const int4v*)&lds[r * DBYTES + chsw(c,     r) * 16];
                    const int4v q1 = *(const int4v*)&lds[r * DBYTES + chsw(c + 1, r) * 16];
                    av[mt][ks][0]=q0[0]; av[mt][ks][1]=q0[1];
                    av[mt][ks][2]=q0[2]; av[mt][ks][3]=q0[3];
                    av[mt][ks][4]=q1[0]; av[mt][ks][5]=q1[1];
                    av[mt][ks][6]=q1[2]; av[mt][ks][7]=q1[3];
                }
            }
            cur_i = i;
            __syncthreads();   // A-frag reads complete before B staging
        }

        // ---- stage B tile j (full K, 64 KB)
        const unsigned char* gB = A + (size_t)j * 128 * DBYTES;
        #pragma unroll
        for (int rnd = 0; rnd < 16; ++rnd) {
            const int r  = rnd * 8 + sr_off;
            const int cl = chsw(scp, r);
            load_lds16(gB + (size_t)r * DBYTES + cl * 16,
                       &lds[r * DBYTES + scp * 16]);
        }
        __syncthreads();

        // ---- compute 128x128 tile: 8 K-steps, B-fragments only from LDS
        float16v acc[2][2];
        #pragma unroll
        for (int a = 0; a < 2; ++a)
            #pragma unroll
            for (int b = 0; b < 2; ++b)
                #pragma unroll
                for (int r = 0; r < 16; ++r) acc[a][b][r] = 0.0f;

        #pragma unroll
        for (int ks = 0; ks < 8; ++ks) {
            const int c = ks * 4 + h * 2;
            int8v bv[2];
            #pragma unroll
            for (int nt = 0; nt < 2; ++nt) {
                const int r = wn * 64 + nt * 32 + lr;
                const int4v q0 = *(const int4v*)&lds[r * DBYTES + chsw(c,     r) * 16];
                const int4v q1 = *(const int4v*)&lds[r * DBYTES + chsw(c + 1, r) * 16];
                bv[nt][0]=q0[0]; bv[nt][1]=q0[1]; bv[nt][2]=q0[2]; bv[nt][3]=q0[3];
                bv[nt][4]=q1[0]; bv[nt][5]=q1[1]; bv[nt][6]=q1[2]; bv[nt][7]=q1[3];
            }
            #pragma unroll
            for (int mt = 0; mt < 2; ++mt)
                #pragma unroll
                for (int nt = 0; nt < 2; ++nt)
                    acc[mt][nt] = __builtin_amdgcn_mfma_scale_f32_32x32x64_f8f6f4(
                        av[mt][ks], bv[nt], acc[mt][nt],
                        0, 0,                       // cbsz=fp8(e4m3), blgp=fp8
                        0, SCALE_SPLAT,             // opsel_a, scale_a (2^-10)
                        0, SCALE_SPLAT);            // opsel_b, scale_b (2^-10)
        }

        // ---- per-tile epilogue: weighted exp-sum into running per-lane s
        const float w = (i == j) ? 1.0f : 2.0f;
        #pragma unroll
        for (int mt = 0; mt < 2; ++mt)
            #pragma unroll
            for (int nt = 0; nt < 2; ++nt)
                #pragma unroll
                for (int r2 = 0; r2 < 16; ++r2) {
                    const float g = acc[mt][nt][r2];
                    s += w * __expf(4.0f * fminf(g, 1.0f) - 4.0f);
                }

        // next triangular tile
        ++j;
        if (j == NT) { ++i; j = i; }
    }

    // ---- block reduction + one atomic into spread accumulators
    #pragma unroll
    for (int off = 32; off; off >>= 1) s += __shfl_down(s, off);
    if (lane == 0) ps[wave] = s;
    __syncthreads();
    if (tid == 0) {
        const float tot = ps[0] + ps[1] + ps[2] + ps[3];
        atomicAdd(&S[blockIdx.y * 32 + (blockIdx.x & 31)], tot);
    }
}

// ---------------------------------------------------------------- finalize
__global__ __launch_bounds__(256) void finalize_kernel(
    const float* __restrict__ S,       // [64]
    const float* __restrict__ alignp,  // [2048]
    float* __restrict__ out)
{
    const int tid = threadIdx.x;
    float a = 0.0f;
    #pragma unroll
    for (int k = 0; k < 8; ++k) a += alignp[tid + 256 * k];
    #pragma unroll
    for (int off = 32; off; off >>= 1) a += __shfl_down(a, off);
    __shared__ float r4[4];
    if ((tid & 63) == 0) r4[tid >> 6] = a;
    __syncthreads();
    if (tid == 0) {
        const double A = (double)r4[0] + r4[1] + r4[2] + r4[3];
        double si = 0.0, st = 0.0;
        for (int k = 0; k < 32; ++k) { si += S[k]; st += S[32 + k]; }
        const double align = 2.0 - 2.0 * A / (double)NROWS;
        const double n2 = (double)NROWS * (double)NROWS;
        const double unif = 0.5 * (log(si / n2) + log(st / n2));
        out[0] = (float)(3.0 * align + unif);
    }
}

// ---------------------------------------------------------------- launch
extern "C" void kernel_launch(void* const* d_in, const int* in_sizes, int n_in,
                              void* d_out, int out_size, void* d_ws, size_t ws_size,
                              hipStream_t stream) {
    const float* img = (const float*)d_in[0];
    const float* txt = (const float*)d_in[1];
    char* ws = (char*)d_ws;
    unsigned char* nimg = (unsigned char*)ws;                             // 4 MB
    unsigned char* ntxt = (unsigned char*)(ws + (size_t)NROWS * DBYTES);  // 4 MB
    float* S      = (float*)(ws + 2 * (size_t)NROWS * DBYTES);            // [64]
    float* alignp = S + 64;                                               // [2048]

    normalize_kernel<<<NROWS / 4, 256, 0, stream>>>(img, txt, nimg, ntxt, alignp, S);
    dim3 grid(NBLK, 2);
    gram_kernel<<<grid, 256, 0, stream>>>(nimg, ntxt, S);
    finalize_kernel<<<1, 256, 0, stream>>>(S, alignp, (float*)d_out);
}

// Round 8
// 123.930 us; speedup vs baseline: 1.9888x; 1.9888x over previous
//
#include <hip/hip_runtime.h>
#include <hip/hip_bf16.h>

// IsolaCLIPLoss: out = 3*align + 0.5*(log-mean-exp uniformity of img Gram + txt Gram)
// N=8192, D=512 fp32 inputs.
//
// R8 changes vs R5 (R7 reg-persistent experiment reverted — it spilled:
// VGPR_Count=128 + 210MB scratch WRITE_SIZE):
//  - gram block tile 256x128 (was 128x128): 4 waves, each 128x64 via 4x2 of
//    32x32 MX-fp8 MFMA. LDS reads/MFMA drop 2.0 -> 1.5 b128, staging bytes
//    per output -25%, barrier drains amortized 2x. No cross-barrier register
//    arrays (operands live only inside one kk step -> no spill).
//  - fragments built by writing int4v halves directly into int8v (no
//    per-element copies -> fewer v_movs; R5 VALUBusy was 42%).
//  - triangular tiling at 256-row panels: block (I,j), j>=2I, 1056 blocks per
//    matrix; each wave's 128-row half has uniform weight {0,1,2}.
//  - KEEP: 128B LDS row stride + chunk^swz(row) swizzle (conflict-free),
//    BK=128, separate normalize/finalize dispatches, spread-S atomics.

#define NROWS 8192
#define DBYTES 512         // row stride in bytes (fp8) == D
#define NT    64           // 8192/128 col-tiles
#define NBLK  1056         // sum_{I=0}^{31} (64-2I) blocks per matrix
#define SCALE_SPLAT 0x75757575   // E8M0 byte 117 = 2^-10, splatted

typedef __attribute__((ext_vector_type(8)))  int   int8v;
typedef __attribute__((ext_vector_type(4)))  int   int4v;
typedef __attribute__((ext_vector_type(16))) float float16v;

__device__ inline void load_lds16(const void* g, void* l) {
    __builtin_amdgcn_global_load_lds(
        (const __attribute__((address_space(1))) void*)g,
        (__attribute__((address_space(3))) void*)l, 16, 0, 0);
}

__device__ inline int swz(int r) { return (r ^ (r >> 3)) & 7; }

// ---------------------------------------------------------------- normalize
__global__ __launch_bounds__(256) void normalize_kernel(
    const float* __restrict__ img, const float* __restrict__ txt,
    unsigned char* __restrict__ nimg, unsigned char* __restrict__ ntxt,
    float* __restrict__ alignp,   // [2048] per-block partial of sum_i ndot_i
    float* __restrict__ S)        // [64] gram accumulators -> zeroed here
{
    if (blockIdx.x == 0 && threadIdx.x < 64) S[threadIdx.x] = 0.0f;

    const int lane = threadIdx.x & 63;
    const int wave = threadIdx.x >> 6;
    const int row  = blockIdx.x * 4 + wave;

    const float4* pi = (const float4*)(img + (size_t)row * 512);
    const float4* pt = (const float4*)(txt + (size_t)row * 512);
    const float4 i0 = pi[lane], i1 = pi[lane + 64];
    const float4 t0 = pt[lane], t1 = pt[lane + 64];

    float ssi = i0.x*i0.x + i0.y*i0.y + i0.z*i0.z + i0.w*i0.w
              + i1.x*i1.x + i1.y*i1.y + i1.z*i1.z + i1.w*i1.w;
    float sst = t0.x*t0.x + t0.y*t0.y + t0.z*t0.z + t0.w*t0.w
              + t1.x*t1.x + t1.y*t1.y + t1.z*t1.z + t1.w*t1.w;
    float dot = i0.x*t0.x + i0.y*t0.y + i0.z*t0.z + i0.w*t0.w
              + i1.x*t1.x + i1.y*t1.y + i1.z*t1.z + i1.w*t1.w;

    #pragma unroll
    for (int off = 1; off < 64; off <<= 1) {
        ssi += __shfl_xor(ssi, off);
        sst += __shfl_xor(sst, off);
        dot += __shfl_xor(dot, off);
    }
    const float inv_i = 1.0f / fmaxf(sqrtf(ssi), 1e-12f);
    const float inv_t = 1.0f / fmaxf(sqrtf(sst), 1e-12f);
    const float si = 1024.0f * inv_i;   // quantize at 2^10 scale
    const float st = 1024.0f * inv_t;

    int p0 = __builtin_amdgcn_cvt_pk_fp8_f32(i0.x*si, i0.y*si, 0, false);
    p0     = __builtin_amdgcn_cvt_pk_fp8_f32(i0.z*si, i0.w*si, p0, true);
    int p1 = __builtin_amdgcn_cvt_pk_fp8_f32(i1.x*si, i1.y*si, 0, false);
    p1     = __builtin_amdgcn_cvt_pk_fp8_f32(i1.z*si, i1.w*si, p1, true);
    int q0 = __builtin_amdgcn_cvt_pk_fp8_f32(t0.x*st, t0.y*st, 0, false);
    q0     = __builtin_amdgcn_cvt_pk_fp8_f32(t0.z*st, t0.w*st, q0, true);
    int q1 = __builtin_amdgcn_cvt_pk_fp8_f32(t1.x*st, t1.y*st, 0, false);
    q1     = __builtin_amdgcn_cvt_pk_fp8_f32(t1.z*st, t1.w*st, q1, true);

    int* oi = (int*)(nimg + (size_t)row * DBYTES);
    int* ot = (int*)(ntxt + (size_t)row * DBYTES);
    oi[lane] = p0; oi[lane + 64] = p1;
    ot[lane] = q0; ot[lane + 64] = q1;

    __shared__ float r4[4];
    if (lane == 0) r4[wave] = dot * inv_i * inv_t;
    __syncthreads();
    if (threadIdx.x == 0)
        alignp[blockIdx.x] = r4[0] + r4[1] + r4[2] + r4[3];
}

// ---------------------------------------------------------------- gram + lme
// Block (I, j): rows [256I, 256I+256) x cols [128j, 128j+128), j >= 2I.
// Wave w: wm = w&1 selects 128-row half, wn = w>>1 selects 64-col half.
// Per-wave weight: r128 = 2I+wm; w = (j>r128)?2:(j==r128)?1:0.
__global__ __launch_bounds__(256, 2) void gram_kernel(
    const unsigned char* __restrict__ A0,   // fp8 [8192][512], blockIdx.y==0
    const unsigned char* __restrict__ A1,   // blockIdx.y==1
    float* __restrict__ S)                  // [64] spread accumulators
{
    // Decode block index b -> (I, j):  cum(I) = I*(65-I), j = 2I + (b - cum(I))
    const int b = blockIdx.x;
    int I = (int)((65.0f - sqrtf(4225.0f - 4.0f * (float)b)) * 0.5f);
    while ((I + 1) * (64 - I) <= b) ++I;
    while (I * (65 - I) > b) --I;
    const int j = 2 * I + (b - I * (65 - I));

    const unsigned char* __restrict__ A = blockIdx.y ? A1 : A0;
    const int tid  = threadIdx.x;
    const int lane = tid & 63;
    const int wave = tid >> 6;
    const int wm = wave & 1, wn = wave >> 1;
    const int lr = lane & 31;                  // row-in-subtile
    const int h  = lane >> 5;                  // K-half select

    const unsigned char* gA = A + (size_t)I * 256 * DBYTES;
    const unsigned char* gB = A + (size_t)j * 128 * DBYTES;

    __shared__ __align__(16) unsigned char ldsA[256 * 128];   // 32 KB
    __shared__ __align__(16) unsigned char ldsB[128 * 128];   // 16 KB

    float16v acc[4][2];
    #pragma unroll
    for (int a = 0; a < 4; ++a)
        #pragma unroll
        for (int c = 0; c < 2; ++c)
            #pragma unroll
            for (int r = 0; r < 16; ++r) acc[a][c][r] = 0.0f;

    for (int k0 = 0; k0 < DBYTES; k0 += 128) {
        // Stage A panel 256x128B (8 rounds) + B tile 128x128B (4 rounds).
        // LDS slot lane-contiguous; global chunk cl = cp ^ swz(r).
        #pragma unroll
        for (int rnd = 0; rnd < 8; ++rnd) {
            const int slot = rnd * 4096 + tid * 16;
            const int r    = slot >> 7;
            const int cp   = (slot >> 4) & 7;
            const int cl   = cp ^ swz(r);
            load_lds16(gA + (size_t)r * DBYTES + k0 + cl * 16, &ldsA[slot]);
        }
        #pragma unroll
        for (int rnd = 0; rnd < 4; ++rnd) {
            const int slot = rnd * 4096 + tid * 16;
            const int r    = slot >> 7;
            const int cp   = (slot >> 4) & 7;
            const int cl   = cp ^ swz(r);
            load_lds16(gB + (size_t)r * DBYTES + k0 + cl * 16, &ldsB[slot]);
        }
        __syncthreads();

        #pragma unroll
        for (int kk = 0; kk < 2; ++kk) {       // two K=64 steps per stage
            const int c0 = kk * 4 + h * 2;     // logical 16B chunk, this lane
            int8v av[4], bv[2];
            #pragma unroll
            for (int mt = 0; mt < 4; ++mt) {
                const int r = wm * 128 + mt * 32 + lr;
                const int s0 = swz(r);
                *((int4v*)&av[mt])     = *(const int4v*)&ldsA[r * 128 + ((c0    ) ^ s0) * 16];
                *((int4v*)&av[mt] + 1) = *(const int4v*)&ldsA[r * 128 + ((c0 + 1) ^ s0) * 16];
            }
            #pragma unroll
            for (int nt = 0; nt < 2; ++nt) {
                const int r = wn * 64 + nt * 32 + lr;
                const int s0 = swz(r);
                *((int4v*)&bv[nt])     = *(const int4v*)&ldsB[r * 128 + ((c0    ) ^ s0) * 16];
                *((int4v*)&bv[nt] + 1) = *(const int4v*)&ldsB[r * 128 + ((c0 + 1) ^ s0) * 16];
            }
            #pragma unroll
            for (int mt = 0; mt < 4; ++mt)
                #pragma unroll
                for (int nt = 0; nt < 2; ++nt)
                    acc[mt][nt] = __builtin_amdgcn_mfma_scale_f32_32x32x64_f8f6f4(
                        av[mt], bv[nt], acc[mt][nt],
                        0, 0,                       // cbsz=fp8(e4m3), blgp=fp8
                        0, SCALE_SPLAT,             // opsel_a, scale_a (2^-10)
                        0, SCALE_SPLAT);            // opsel_b, scale_b (2^-10)
        }
        __syncthreads();
    }

    // Epilogue: per-wave uniform symmetry weight, exp-sum, block reduce.
    const int r128 = 2 * I + wm;
    const float wv = (j > r128) ? 2.0f : ((j == r128) ? 1.0f : 0.0f);
    float s = 0.0f;
    #pragma unroll
    for (int mt = 0; mt < 4; ++mt)
        #pragma unroll
        for (int nt = 0; nt < 2; ++nt)
            #pragma unroll
            for (int r2 = 0; r2 < 16; ++r2) {
                const float g = acc[mt][nt][r2];
                s += __expf(4.0f * fminf(g, 1.0f) - 4.0f);
            }
    s *= wv;
    #pragma unroll
    for (int off = 32; off; off >>= 1) s += __shfl_down(s, off);
    __shared__ float ps[4];
    if (lane == 0) ps[wave] = s;
    __syncthreads();
    if (tid == 0) {
        const float tot = ps[0] + ps[1] + ps[2] + ps[3];
        atomicAdd(&S[blockIdx.y * 32 + (blockIdx.x & 31)], tot);
    }
}

// ---------------------------------------------------------------- finalize
__global__ __launch_bounds__(256) void finalize_kernel(
    const float* __restrict__ S,       // [64]
    const float* __restrict__ alignp,  // [2048]
    float* __restrict__ out)
{
    const int tid = threadIdx.x;
    float a = 0.0f;
    #pragma unroll
    for (int k = 0; k < 8; ++k) a += alignp[tid + 256 * k];
    #pragma unroll
    for (int off = 32; off; off >>= 1) a += __shfl_down(a, off);
    __shared__ float r4[4];
    if ((tid & 63) == 0) r4[tid >> 6] = a;
    __syncthreads();
    if (tid == 0) {
        const double A = (double)r4[0] + r4[1] + r4[2] + r4[3];
        double si = 0.0, st = 0.0;
        for (int k = 0; k < 32; ++k) { si += S[k]; st += S[32 + k]; }
        const double align = 2.0 - 2.0 * A / (double)NROWS;
        const double n2 = (double)NROWS * (double)NROWS;
        const double unif = 0.5 * (log(si / n2) + log(st / n2));
        out[0] = (float)(3.0 * align + unif);
    }
}

// ---------------------------------------------------------------- launch
extern "C" void kernel_launch(void* const* d_in, const int* in_sizes, int n_in,
                              void* d_out, int out_size, void* d_ws, size_t ws_size,
                              hipStream_t stream) {
    const float* img = (const float*)d_in[0];
    const float* txt = (const float*)d_in[1];
    char* ws = (char*)d_ws;
    unsigned char* nimg = (unsigned char*)ws;                             // 4 MB
    unsigned char* ntxt = (unsigned char*)(ws + (size_t)NROWS * DBYTES);  // 4 MB
    float* S      = (float*)(ws + 2 * (size_t)NROWS * DBYTES);            // [64]
    float* alignp = S + 64;                                               // [2048]

    normalize_kernel<<<NROWS / 4, 256, 0, stream>>>(img, txt, nimg, ntxt, alignp, S);
    dim3 grid(NBLK, 2);
    gram_kernel<<<grid, 256, 0, stream>>>(nimg, ntxt, S);
    finalize_kernel<<<1, 256, 0, stream>>>(S, alignp, (float*)d_out);
}